// Round 7
// baseline (330.299 us; speedup 1.0000x reference)
//
#include <hip/hip_runtime.h>
#include <cstdint>
#include <cstddef>

typedef __bf16 bf16_t;
typedef bf16_t bf16x8 __attribute__((ext_vector_type(8)));
typedef bf16_t bf16x4 __attribute__((ext_vector_type(4)));
typedef float f32x4 __attribute__((ext_vector_type(4)));

#define B_SZ    4
#define LSEQ    2048
#define DMODEL  1024
#define EDIM    2048
#define ZDIM    4419
#define ZPAD    4608            /* padded to 18 x 256 tiles */
#define ROWS    (B_SZ*LSEQ)     /* 8192 */
#define EPSV    1e-5f

/* padded leading dims (break power-of-2 L2-set/channel aliasing) */
#define LDU     1088            /* ubf, winbf rows of K=1024 */
#define LDG     2112            /* gbuf, woutbf rows of K=2048 */

#define SCHUNK  128             /* scan chunks per batch */
#define SCLEN   (LSEQ/SCHUNK)   /* 16 */
#define RCH     128             /* rope chunks per batch */
#define RCLEN   (LSEQ/RCH)      /* 16 */

// ---------------- helpers ----------------
__device__ __forceinline__ float softplus_f(float x){
  return fmaxf(x, 0.f) + log1pf(expf(-fabsf(x)));
}
__device__ __forceinline__ float sigmoid_f(float x){ return 1.f/(1.f+expf(-x)); }
__device__ __forceinline__ float silu_f(float x){ return x/(1.f+expf(-x)); }

__device__ __forceinline__ void gload_lds16(const void* g, void* l){
  __builtin_amdgcn_global_load_lds(
      (const __attribute__((address_space(1))) void*)g,
      (__attribute__((address_space(3))) void*)l, 16, 0, 0);
}

__device__ __forceinline__ float blockReduce128(float v, float* red, int t){
  red[t] = v; __syncthreads();
  #pragma unroll
  for (int off = 64; off > 0; off >>= 1){
    if (t < off) red[t] += red[t+off];
    __syncthreads();
  }
  float r = red[0];
  __syncthreads();
  return r;
}

// ---------------- kernel 0: vectorized casts + zero accumulators -----------
__global__ __launch_bounds__(256) void prep_kernel(
    const float4* __restrict__ u4, const float4* __restrict__ win4,
    const float4* __restrict__ wout4,
    bf16_t* __restrict__ ubf, bf16_t* __restrict__ winbf, bf16_t* __restrict__ woutbf,
    float* __restrict__ Asum, float* __restrict__ xraw)
{
  size_t i = (size_t)blockIdx.x*256 + threadIdx.x;   // float4 index
  if (i == 0) Asum[0] = 0.f;
  if (i < ROWS) xraw[i] = 0.f;
  const size_t NU4 = (size_t)ROWS*DMODEL/4;
  const size_t NW4 = (size_t)ZPAD*DMODEL/4;
  const size_t NO4 = (size_t)DMODEL*EDIM/4;
  if (i < NU4){
    float4 v = u4[i];
    size_t e = i*4, row = e>>10, col = e&1023;
    bf16x4 o = { (bf16_t)v.x, (bf16_t)v.y, (bf16_t)v.z, (bf16_t)v.w };
    *(bf16x4*)&ubf[row*LDU + col] = o;
    return;
  }
  i -= NU4;
  if (i < NW4){
    size_t e = i*4, row = e>>10, col = e&1023;
    bf16x4 o;
    if (row < (size_t)ZDIM){
      float4 v = win4[i];
      o = bf16x4{ (bf16_t)v.x, (bf16_t)v.y, (bf16_t)v.z, (bf16_t)v.w };
    } else {
      o = bf16x4{ (bf16_t)0.f, (bf16_t)0.f, (bf16_t)0.f, (bf16_t)0.f };
    }
    *(bf16x4*)&winbf[row*LDU + col] = o;
    return;
  }
  i -= NW4;
  if (i < NO4){
    float4 v = wout4[i];
    size_t e = i*4, row = e>>11, col = e&2047;
    bf16x4 o = { (bf16_t)v.x, (bf16_t)v.y, (bf16_t)v.z, (bf16_t)v.w };
    *(bf16x4*)&woutbf[row*LDG + col] = o;
  }
}

// ------------- fine-interleaved 3-buffer GEMM (T1+T2+T3/T4+T5) -------------
// C = A[M][lda] @ W[N][ldw]^T (bf16 row-major, K = NT*64).
// BM=128, BN=256, BK=64, 512 thr = 8 waves (2M x 4N), per-wave 64x64 output.
// 3 LDS buffers (144 KB) -> staging NEVER targets a buffer being read
// (tile t -> buf t%3; stage t+2 during tile t). Per K-tile: 2 fine phases
//   { 8 x ds_read(k-step) | ~3 staging gloads | barrier |
//     lgkmcnt(0)+sched_barrier | setprio(1) 16 MFMA setprio(0) | barrier }
// Tile-boundary gate: vmcnt(6) = allow only tile t+2's 6 just-issued loads
// in flight (tile t+1's loads, issued a full tile earlier, forced landed).
// Never drains to 0 in steady state. T2 chunk-XOR swizzle both sides;
// bijective XCD swizzle.
// MODE 0 (GEMM1): x-region -> silu row-sum atomics into xraw;
//   gate -> silu -> o_g (stride LDG); z -> o_z fp32.
// MODE 1 (GEMM2): out = acc * scale[row] -> o_f fp32 (stride DMODEL).
template<int NT, int NXT, int MODE>
__global__ __launch_bounds__(512, 2) void gemm8P_kernel(
    const bf16_t* __restrict__ A, const int lda,
    const bf16_t* __restrict__ W, const int ldw,
    float* __restrict__ xraw, bf16_t* __restrict__ o_g, float* __restrict__ o_z,
    const float* __restrict__ scale, float* __restrict__ o_f)
{
  constexpr int BM = 128, BN = 256;
  constexpr int MR = 4, NR = 4;
  constexpr int BUFE = (BM+BN)*64;
  __shared__ __align__(16) bf16_t lds[BUFE*3];

  const int tid = threadIdx.x;
  const int wid = tid>>6, lane = tid&63;
  const int wr = wid>>2, wc = wid&3;
  const int lr = lane&15;

  const int nwg = NXT*(ROWS/BM);
  const int id = blockIdx.x;
  const int rid = (id & 7)*(nwg>>3) + (id>>3);   // bijective: nwg % 8 == 0
  const int bx = rid % NXT, by = rid / NXT;
  const int m0 = by*BM, n0 = bx*BN;

  f32x4 acc[MR][NR] = {};

  auto stageA = [&](int buf, int t){              // 2 loads/thread
    bf16_t* lA = lds + buf*BUFE;
    const int k0 = t*64;
    #pragma unroll
    for (int q = 0; q < BM/64; ++q){
      int cidx = q*512 + tid;
      int row = cidx>>3, sc = (cidx&7) ^ (row&7);
      gload_lds16(A + (size_t)(m0+row)*lda + k0 + sc*8,
                  lA + (size_t)(q*512 + wid*64)*8);
    }
  };
  auto stageB = [&](int buf, int t){              // 4 loads/thread
    bf16_t* lB = lds + buf*BUFE + BM*64;
    const int k0 = t*64;
    #pragma unroll
    for (int q = 0; q < BN/64; ++q){
      int cidx = q*512 + tid;
      int row = cidx>>3, sc = (cidx&7) ^ (row&7);
      gload_lds16(W + (size_t)(n0+row)*ldw + k0 + sc*8,
                  lB + (size_t)(q*512 + wid*64)*8);
    }
  };
  auto dsread = [&](int buf, int kk, bf16x8* af, bf16x8* bfr){
    const bf16_t* lA = lds + buf*BUFE;
    const bf16_t* lB = lA + BM*64;
    const int g = kk*4 + (lane>>4);
    #pragma unroll
    for (int n = 0; n < NR; ++n){
      int rr = wc*64 + n*16 + lr;
      bfr[n] = *(const bf16x8*)&lB[rr*64 + ((g^(rr&7))<<3)];
    }
    #pragma unroll
    for (int m = 0; m < MR; ++m){
      int rr = wr*64 + m*16 + lr;
      af[m] = *(const bf16x8*)&lA[rr*64 + ((g^(rr&7))<<3)];
    }
  };

  // prologue: tiles 0 and 1 fully staged; tile 0 forced landed.
  stageA(0, 0); stageB(0, 0);
  stageA(1, 1); stageB(1, 1);
  asm volatile("s_waitcnt vmcnt(6)" ::: "memory");
  __builtin_amdgcn_s_barrier();

  int cur = 0;
  for (int t = 0; t < NT; ++t){
    int nb = cur + 2; if (nb >= 3) nb -= 3;
    const bool pf = (t+2 < NT);
    // ---- phase 0 (k-step 0) ----
    {
      bf16x8 af[MR], bfr[NR];
      dsread(cur, 0, af, bfr);
      if (pf) stageA(nb, t+2);
      __builtin_amdgcn_s_barrier();
      asm volatile("s_waitcnt lgkmcnt(0)" ::: "memory");
      __builtin_amdgcn_sched_barrier(0);
      __builtin_amdgcn_s_setprio(1);
      #pragma unroll
      for (int m = 0; m < MR; ++m)
        #pragma unroll
        for (int n = 0; n < NR; ++n)
          acc[m][n] = __builtin_amdgcn_mfma_f32_16x16x32_bf16(af[m], bfr[n], acc[m][n], 0,0,0);
      __builtin_amdgcn_s_setprio(0);
      __builtin_amdgcn_s_barrier();
    }
    // ---- phase 1 (k-step 1) ----
    {
      bf16x8 af[MR], bfr[NR];
      dsread(cur, 1, af, bfr);
      if (pf){
        stageB(nb, t+2);
        asm volatile("s_waitcnt vmcnt(6)" ::: "memory");  // t+1 landed; t+2 in flight
      } else {
        asm volatile("s_waitcnt vmcnt(0)" ::: "memory");
      }
      __builtin_amdgcn_s_barrier();
      asm volatile("s_waitcnt lgkmcnt(0)" ::: "memory");
      __builtin_amdgcn_sched_barrier(0);
      __builtin_amdgcn_s_setprio(1);
      #pragma unroll
      for (int m = 0; m < MR; ++m)
        #pragma unroll
        for (int n = 0; n < NR; ++n)
          acc[m][n] = __builtin_amdgcn_mfma_f32_16x16x32_bf16(af[m], bfr[n], acc[m][n], 0,0,0);
      __builtin_amdgcn_s_setprio(0);
      __builtin_amdgcn_s_barrier();
    }
    if (++cur == 3) cur = 0;
  }

  // ---- epilogue (branch uniform per block: region boundaries 256-aligned)
  if (MODE == 0 && n0 < 2048){
    // x region: only the per-row silu mean is needed downstream
    #pragma unroll
    for (int m = 0; m < MR; ++m){
      #pragma unroll
      for (int i = 0; i < 4; ++i){
        float p = 0.f;
        #pragma unroll
        for (int n = 0; n < NR; ++n) p += silu_f(acc[m][n][i]);
        #pragma unroll
        for (int off = 8; off > 0; off >>= 1) p += __shfl_xor(p, off);
        if (lr == 0){
          int r = m0 + wr*64 + m*16 + ((lane>>4)<<2) + i;
          atomicAdd(xraw + r, p);
        }
      }
    }
  } else {
    #pragma unroll
    for (int m = 0; m < MR; ++m){
      int rowb = m0 + wr*64 + m*16 + ((lane>>4)<<2);
      #pragma unroll
      for (int n = 0; n < NR; ++n){
        int col = n0 + wc*64 + n*16 + lr;
        #pragma unroll
        for (int i = 0; i < 4; ++i){
          int r = rowb + i;
          float v = acc[m][n][i];
          if (MODE == 0){
            if (col < 4096)      o_g[(size_t)r*LDG + (col-2048)] = (bf16_t)silu_f(v);
            else if (col < 4480) o_z[(size_t)r*384 + (col-4096)] = v;
          } else {
            o_f[(size_t)r*DMODEL + col] = v * scale[r];
          }
        }
      }
    }
  }
}

// ---------------- kernel 2: per-token fuse (RMS + scalars) ----------------
__global__ __launch_bounds__(128) void fuse_kernel(
    const float* __restrict__ xraw, const float* __restrict__ zs,
    const float* __restrict__ wnB, const float* __restrict__ wnC,
    const float* __restrict__ Bb, const float* __restrict__ Cb,
    const float* __restrict__ dtb, const float* __restrict__ Alog,
    float* __restrict__ Bn, float* __restrict__ Cn, float* __restrict__ dtth,
    float* __restrict__ dts, float* __restrict__ alphas, float* __restrict__ lams,
    float* __restrict__ xbar, float* Asum)
{
  __shared__ float red[128];
  int r = blockIdx.x, t = threadIdx.x;
  const float* zr = zs + (size_t)r*384;
  float bv = zr[t], cv = zr[128+t];
  float b2 = blockReduce128(bv*bv, red, t);
  float c2 = blockReduce128(cv*cv, red, t);
  float rb = rsqrtf(b2*(1.f/128.f) + EPSV);
  float rc = rsqrtf(c2*(1.f/128.f) + EPSV);
  Bn[(size_t)r*128 + t] = bv*rb*wnB[t] + Bb[t];
  Cn[(size_t)r*128 + t] = cv*rc*wnC[t] + Cb[t];

  float dt = softplus_f(zr[256] + dtb[0]);
  if (t < 64) dtth[(size_t)r*64 + t] = dt * zr[258+t];
  if (t == 0){
    float Av  = -softplus_f(zr[257] + Alog[0]);
    float lam = sigmoid_f(zr[322]);
    dts[r]    = dt;
    alphas[r] = expf(dt*Av);
    lams[r]   = lam;
    xbar[r]   = xraw[r] * (1.f/2048.f);
    atomicAdd(Asum, Av);
  }
}

// ---------------- kernel 3a: per-chunk angle sums ----------------
__global__ __launch_bounds__(64) void rope_sum_kernel(
    const float* __restrict__ dtth, float* __restrict__ csum)
{
  int b  = blockIdx.x >> 7;
  int ch = blockIdx.x & 127;
  int d  = threadIdx.x;
  const float* base = dtth + ((size_t)b*LSEQ + (size_t)ch*RCLEN)*64 + d;
  float s = 0.f;
  #pragma unroll
  for (int i = 0; i < RCLEN; ++i) s += base[(size_t)i*64];
  csum[((size_t)b*RCH + ch)*64 + d] = s;
}

// ---------------- kernel 3b: exclusive prefix over chunks (in place) -------
__global__ __launch_bounds__(64) void rope_prefix_kernel(float* __restrict__ csum)
{
  int b = blockIdx.x, d = threadIdx.x;
  float s = 0.f;
  for (int c = 0; c < RCH; ++c){
    size_t idx = ((size_t)b*RCH + c)*64 + d;
    float v = csum[idx]; csum[idx] = s; s += v;
  }
}

// ---------------- kernel 3c: rope apply with chunk offsets ----------------
__global__ __launch_bounds__(64) void rope_apply_kernel(
    const float* __restrict__ dtth, const float* __restrict__ csum,
    float* __restrict__ Bn, float* __restrict__ Cn)
{
  int b  = blockIdx.x >> 7;
  int ch = blockIdx.x & 127;
  int d  = threadIdx.x;
  float ca = csum[((size_t)b*RCH + ch)*64 + d];
  int l0 = ch*RCLEN;
  const float* base = dtth + ((size_t)b*LSEQ)*64 + d;
  for (int l = l0; l < l0 + RCLEN; ++l){
    ca += base[(size_t)l*64];
    float sn, cs;
    sincosf(ca, &sn, &cs);
    size_t ro = ((size_t)b*LSEQ + l)*128;
    float b1 = Bn[ro+d], b2v = Bn[ro+64+d];
    Bn[ro+d]    = b1*cs - b2v*sn;
    Bn[ro+64+d] = b1*sn + b2v*cs;
    float c1 = Cn[ro+d], c2v = Cn[ro+64+d];
    Cn[ro+d]    = c1*cs - c2v*sn;
    Cn[ro+64+d] = c1*sn + c2v*cs;
  }
}

// ---------------- kernel 4a: chunk-local scan ----------------
__global__ __launch_bounds__(64) void scan_local_kernel(
    const float* __restrict__ dts, const float* __restrict__ alphas,
    const float* __restrict__ lams, const float* __restrict__ xbar,
    const float* __restrict__ Asum,
    const float* __restrict__ Bn, const float* __restrict__ Cn,
    float* __restrict__ ylocal, float* __restrict__ Pfix,
    float* __restrict__ Sfin, float* __restrict__ Dch)
{
  int b  = blockIdx.x / SCHUNK;
  int ch = blockIdx.x % SCHUNK;
  int n  = threadIdx.x;
  float Abar = Asum[0] * (1.f/(float)ROWS);
  float s1 = 0.f, s2 = 0.f, P = 1.f;
  int l0 = ch*SCLEN;
  #pragma unroll
  for (int i = 0; i < SCLEN; ++i){
    int l = l0 + i;
    size_t r = (size_t)b*LSEQ + l;
    float dt = dts[r], lam = lams[r], al = alphas[r], xb = xbar[r];
    float xp = (l > 0) ? xbar[r-1] : 0.f;
    float um = lam*xb + (1.f-lam)*al*xp;
    float dA = expf(dt*Abar);
    float coef = dt*um;
    size_t ro = r*128;
    s1 = dA*s1 + coef*Bn[ro+n];
    s2 = dA*s2 + coef*Bn[ro+64+n];
    P *= dA;
    float p = s1*Cn[ro+n] + s2*Cn[ro+64+n];
    #pragma unroll
    for (int off = 32; off > 0; off >>= 1) p += __shfl_down(p, off);
    if (n == 0){ ylocal[r] = p; Pfix[r] = P; }
  }
  size_t so = ((size_t)b*SCHUNK + ch)*128;
  Sfin[so + n]      = s1;
  Sfin[so + 64 + n] = s2;
  if (n == 0) Dch[b*SCHUNK + ch] = P;
}

// ---------------- kernel 4b: inter-chunk carry ----------------
__global__ __launch_bounds__(128) void scan_carry_kernel(
    const float* __restrict__ Sfin, const float* __restrict__ Dch,
    float* __restrict__ Sin)
{
  int b = blockIdx.x;
  int n = threadIdx.x;   // 0..127
  float s = 0.f;
  for (int c = 0; c < SCHUNK; ++c){
    size_t so = ((size_t)b*SCHUNK + c)*128;
    Sin[so + n] = s;
    s = Dch[b*SCHUNK + c]*s + Sfin[so + n];
  }
}

// ---------------- kernel 4c: fixup  y = y_local + P_l * (C_l . Sin) --------
__global__ __launch_bounds__(256) void scan_fix_kernel(
    const float* __restrict__ Cn, const float* __restrict__ Sin,
    const float* __restrict__ ylocal, const float* __restrict__ Pfix,
    float* __restrict__ outsv)
{
  int r = blockIdx.x*4 + (threadIdx.x>>6);
  int n = threadIdx.x & 63;
  int b  = r / LSEQ;
  int ch = (r % LSEQ) / SCLEN;
  const float* si = Sin + ((size_t)b*SCHUNK + ch)*128;
  size_t ro = (size_t)r*128;
  float p = Cn[ro+n]*si[n] + Cn[ro+64+n]*si[64+n];
  #pragma unroll
  for (int off = 32; off > 0; off >>= 1) p += __shfl_down(p, off);
  if (n == 0) outsv[r] = ylocal[r] + Pfix[r]*p;
}

// ---------------- launch ----------------
extern "C" void kernel_launch(void* const* d_in, const int* in_sizes, int n_in,
                              void* d_out, int out_size, void* d_ws, size_t ws_size,
                              hipStream_t stream)
{
  const float* u    = (const float*)d_in[0];
  const float* W_in = (const float*)d_in[1];
  const float* wnB  = (const float*)d_in[2];
  const float* wnC  = (const float*)d_in[3];
  const float* Bb   = (const float*)d_in[4];
  const float* Cb   = (const float*)d_in[5];
  const float* dtb  = (const float*)d_in[6];
  const float* Alog = (const float*)d_in[7];
  const float* Wout = (const float*)d_in[8];
  float* out = (float*)d_out;
  char* ws = (char*)d_ws;

  constexpr size_t OFF_ASUM = 0;
  constexpr size_t OFF_UBF  = 256;
  constexpr size_t SZ_UBF   = (size_t)ROWS*LDU*2;
  constexpr size_t OFF_WIN  = OFF_UBF + SZ_UBF;
  constexpr size_t SZ_WIN   = (size_t)ZPAD*LDU*2;
  constexpr size_t OFF_WOUT = OFF_WIN + SZ_WIN;
  constexpr size_t SZ_WOUT  = (size_t)DMODEL*LDG*2;
  constexpr size_t OFF_G    = OFF_WOUT + SZ_WOUT;
  constexpr size_t SZ_G     = (size_t)ROWS*LDG*2;
  constexpr size_t OFF_ZS   = OFF_G + SZ_G;
  constexpr size_t SZ_ZS    = (size_t)ROWS*384*4;
  constexpr size_t OFF_BN   = OFF_ZS + SZ_ZS;
  constexpr size_t SZ_BN    = (size_t)ROWS*128*4;
  constexpr size_t OFF_CN   = OFF_BN + SZ_BN;
  constexpr size_t OFF_DTTH = OFF_CN + SZ_BN;
  constexpr size_t SZ_DTTH  = (size_t)ROWS*64*4;
  constexpr size_t OFF_XRAW = OFF_DTTH + SZ_DTTH;
  constexpr size_t OFF_DT   = OFF_XRAW + (size_t)ROWS*4;
  constexpr size_t OFF_AL   = OFF_DT  + (size_t)ROWS*4;
  constexpr size_t OFF_LAM  = OFF_AL  + (size_t)ROWS*4;
  constexpr size_t OFF_XB   = OFF_LAM + (size_t)ROWS*4;
  constexpr size_t OFF_OUTS = OFF_XB  + (size_t)ROWS*4;
  constexpr size_t OFF_YLOC = OFF_OUTS + (size_t)ROWS*4;
  constexpr size_t OFF_PFIX = OFF_YLOC + (size_t)ROWS*4;
  constexpr size_t OFF_SFIN = OFF_PFIX + (size_t)ROWS*4;
  constexpr size_t SZ_SFIN  = (size_t)B_SZ*SCHUNK*128*4;
  constexpr size_t OFF_DCH  = OFF_SFIN + SZ_SFIN;
  constexpr size_t OFF_SIN  = OFF_DCH + (size_t)B_SZ*SCHUNK*4;
  constexpr size_t OFF_CSUM = OFF_SIN + SZ_SFIN;

  float*  Asum   = (float*) (ws + OFF_ASUM);
  bf16_t* ubf    = (bf16_t*)(ws + OFF_UBF);
  bf16_t* winbf  = (bf16_t*)(ws + OFF_WIN);
  bf16_t* woutbf = (bf16_t*)(ws + OFF_WOUT);
  bf16_t* gbuf   = (bf16_t*)(ws + OFF_G);
  float*  zsb    = (float*) (ws + OFF_ZS);
  float*  Bn     = (float*) (ws + OFF_BN);
  float*  Cn     = (float*) (ws + OFF_CN);
  float*  dtth   = (float*) (ws + OFF_DTTH);
  float*  xraw   = (float*) (ws + OFF_XRAW);
  float*  dts    = (float*) (ws + OFF_DT);
  float*  alphas = (float*) (ws + OFF_AL);
  float*  lams   = (float*) (ws + OFF_LAM);
  float*  xbar   = (float*) (ws + OFF_XB);
  float*  outsv  = (float*) (ws + OFF_OUTS);
  float*  ylocal = (float*) (ws + OFF_YLOC);
  float*  Pfix   = (float*) (ws + OFF_PFIX);
  float*  Sfin   = (float*) (ws + OFF_SFIN);
  float*  Dch    = (float*) (ws + OFF_DCH);
  float*  Sin    = (float*) (ws + OFF_SIN);
  float*  csum   = (float*) (ws + OFF_CSUM);

  {
    size_t total4 = ((size_t)ROWS*DMODEL + (size_t)ZPAD*DMODEL + (size_t)DMODEL*EDIM)/4;
    int blocks = (int)((total4 + 255)/256);
    prep_kernel<<<blocks, 256, 0, stream>>>(
        (const float4*)u, (const float4*)W_in, (const float4*)Wout,
        ubf, winbf, woutbf, Asum, xraw);
  }
  // GEMM1: 128x256 tile, grid = 18 x 64 = 1152 blocks (nwg%8==0)
  gemm8P_kernel<DMODEL/64, ZPAD/256, 0>
      <<<(ZPAD/256)*(ROWS/128), 512, 0, stream>>>(
      ubf, LDU, winbf, LDU, xraw, gbuf, zsb, nullptr, nullptr);
  fuse_kernel<<<ROWS, 128, 0, stream>>>(xraw, zsb, wnB, wnC, Bb, Cb, dtb, Alog,
                                        Bn, Cn, dtth, dts, alphas, lams, xbar, Asum);
  rope_sum_kernel<<<B_SZ*RCH, 64, 0, stream>>>(dtth, csum);
  rope_prefix_kernel<<<B_SZ, 64, 0, stream>>>(csum);
  rope_apply_kernel<<<B_SZ*RCH, 64, 0, stream>>>(dtth, csum, Bn, Cn);
  scan_local_kernel<<<B_SZ*SCHUNK, 64, 0, stream>>>(dts, alphas, lams, xbar, Asum,
                                                    Bn, Cn, ylocal, Pfix, Sfin, Dch);
  scan_carry_kernel<<<B_SZ, 128, 0, stream>>>(Sfin, Dch, Sin);
  scan_fix_kernel<<<ROWS/4, 256, 0, stream>>>(Cn, Sin, ylocal, Pfix, outsv);
  // GEMM2: 128x256 tile, grid = 4 x 64 = 256 blocks = 1/CU
  gemm8P_kernel<EDIM/64, DMODEL/256, 1>
      <<<(DMODEL/256)*(ROWS/128), 512, 0, stream>>>(
      gbuf, LDG, woutbf, LDG, nullptr, nullptr, nullptr, outsv, out);
}